// Round 2
// baseline (1667.465 us; speedup 1.0000x reference)
//
#include <hip/hip_runtime.h>
#include <hip/hip_bf16.h>
#include <math.h>

// DeepseekV2-Lite decoder layer, MI355X gfx950.
// Round 6: all GEMMs moved to a 512-thread, BK=32, 4-deep circular-buffer
// pipelined kernel with counted s_waitcnt vmcnt(N) (never 0 in steady state),
// s_setprio around the MFMA cluster, 2-way-max LDS XOR swizzle, and bijective
// XCD-aware block swizzle. BM=256 for large-N GEMMs, BM=128 for N=2048 ones
// (keeps grid at 256 blocks).
//
// Shapes: B=2 S=2048 T=4096, H=16, D_NOPE=128 D_ROPE=64 D_Q=192 D_V=128,
// KV_RANK=512, HID=2048, INTER=10944.

typedef short short8 __attribute__((ext_vector_type(8)));
typedef short short4v __attribute__((ext_vector_type(4)));
typedef float f32x4 __attribute__((ext_vector_type(4)));

static __device__ __forceinline__ float bf2f(ushort u) {
  union { uint i; float f; } v; v.i = ((uint)u) << 16; return v.f;
}
static __device__ __forceinline__ ushort f2bf(float x) {
  union { float f; uint i; } v; v.f = x;
  uint r = v.i + 0x7fffu + ((v.i >> 16) & 1u);
  return (ushort)(r >> 16);
}

// async global->LDS, 16B per lane; LDS dest is wave-uniform base + lane*16
static __device__ __forceinline__ void glds16(const ushort* g, ushort* l) {
  __builtin_amdgcn_global_load_lds(
      (const __attribute__((address_space(1))) unsigned int*)g,
      (__attribute__((address_space(3))) unsigned int*)l, 16, 0, 0);
}

#define WAITVM(N) asm volatile("s_waitcnt vmcnt(%0)" ::"n"(N) : "memory")

// ---------------- fp32 -> bf16 weight conversion ----------------
__global__ __launch_bounds__(256)
void cvt_bf16(const float* __restrict__ in, ushort* __restrict__ out, int n8) {
  int i = blockIdx.x * 256 + threadIdx.x;
  if (i >= n8) return;
  float4 a = ((const float4*)in)[2 * i];
  float4 b = ((const float4*)in)[2 * i + 1];
  short8 o;
  o[0] = (short)f2bf(a.x); o[1] = (short)f2bf(a.y);
  o[2] = (short)f2bf(a.z); o[3] = (short)f2bf(a.w);
  o[4] = (short)f2bf(b.x); o[5] = (short)f2bf(b.y);
  o[6] = (short)f2bf(b.z); o[7] = (short)f2bf(b.w);
  ((short8*)out)[i] = o;
}

// ---------------- RMSNorm (fp32 in -> bf16 out) ----------------
__global__ __launch_bounds__(256)
void rms_bf16(const float* __restrict__ in, int istride, int width, float inv_w,
              const float* __restrict__ w, ushort* __restrict__ out, int ostride) {
  const int row = blockIdx.x;
  const float* x = in + (size_t)row * istride;
  float ss = 0.f;
  for (int i = threadIdx.x; i < width; i += 256) { float v = x[i]; ss += v * v; }
#pragma unroll
  for (int off = 32; off > 0; off >>= 1) ss += __shfl_xor(ss, off);
  __shared__ float red[4];
  if ((threadIdx.x & 63) == 0) red[threadIdx.x >> 6] = ss;
  __syncthreads();
  float tot = red[0] + red[1] + red[2] + red[3];
  float scale = rsqrtf(tot * inv_w + 1e-6f);
  ushort* o = out + (size_t)row * ostride;
  for (int i = threadIdx.x; i < width; i += 256) o[i] = f2bf(x[i] * scale * w[i]);
}

// ---------------- Pipelined GEMM: C[M,N] = A[M,K](bf16) @ B[N,K]^T(bf16) ----
// 512 threads = 8 waves (2 M-groups x 4 N-groups). BN = 256 fixed.
// BMH selects BM = BMH*128. BK = 32 (one 16x16x32 k-step per tile).
// 4 LDS buffers, prefetch depth 3, counted vmcnt (3*LPT in steady state).
// LDS swizzle: 16B slot s of row r holds global unit s ^ (r&3) ^ ((r>>2)&3)
// -> 2-way max bank aliasing on ds_read_b128 (free, m136).
// EPI 0: C bf16 ; EPI 2: C f32 = acc + res(f32)
// EPI 3: C bf16 = silu(prev bf16 at resv) * acc
// EPI 4: split QKV epilogue (cols <3072 -> bf16 q stride 3072; else f32 ckv
//        stride 576 at resv)
template<int EPI, int BMH>
__global__ __launch_bounds__(512, 2)
void gemm256(const ushort* __restrict__ A, const ushort* __restrict__ B,
             void* __restrict__ Cv, const void* __restrict__ resv,
             int M, int N, int K) {
  constexpr int BM  = BMH * 128;
  constexpr int MR  = BMH * 4;      // m-frags per wave
  constexpr int LPT = BMH + 2;      // glds16 per thread per K-tile
  __shared__ __align__(16) ushort As[4][BM * 32];   // 32/64 KB
  __shared__ __align__(16) ushort Bs[4][256 * 32];  // 64 KB
  const int tid = threadIdx.x;
  const int wave = tid >> 6, lane = tid & 63;
  const int lm = lane & 15, quad = lane >> 4;

  // bijective XCD-aware block swizzle (m204)
  const int gx = gridDim.x;
  int wg = blockIdx.y * gx + blockIdx.x;
  {
    const int nwg = gx * (int)gridDim.y;
    const int q = nwg >> 3, r = nwg & 7;
    const int xcd = wg & 7, i = wg >> 3;
    wg = (xcd < r ? xcd * (q + 1) : r * (q + 1) + (xcd - r) * q) + i;
  }
  const int m0 = (wg % gx) * BM, n0 = (wg / gx) * 256;

  const int wmg = wave >> 2, wng = wave & 3;
  const int am = wmg * (BM / 2);    // wave's A-row base for frag reads
  const int bn = wng * 64;          // wave's B-row (C-col) base

  // ---- staging addresses: per wave-instruction = 16 rows x 32 cols (1 KB)
  const int srow = lane >> 2;                       // row within 16-row group
  const int gu = (lane & 3) ^ (srow & 3) ^ ((srow >> 2) & 3);  // swizzled unit
  const ushort* gA[BMH];
  ushort* lA[BMH];
#pragma unroll
  for (int j = 0; j < BMH; ++j) {
    const int r = wave * (16 * BMH) + j * 16;
    gA[j] = A + (size_t)(m0 + r + srow) * K + gu * 8;
    lA[j] = &As[0][0] + r * 32;
  }
  const ushort* gB[2];
  ushort* lB[2];
#pragma unroll
  for (int j = 0; j < 2; ++j) {
    const int r = wave * 32 + j * 16;
    int br = n0 + r + srow; if (br > N - 1) br = N - 1;  // clamp (cols guarded)
    gB[j] = B + (size_t)br * K + gu * 8;
    lB[j] = &Bs[0][0] + r * 32;
  }

  auto stage = [&](int t) {
    const int b = t & 3;
#pragma unroll
    for (int j = 0; j < BMH; ++j) glds16(gA[j] + t * 32, lA[j] + b * (BM * 32));
#pragma unroll
    for (int j = 0; j < 2; ++j)  glds16(gB[j] + t * 32, lB[j] + b * (256 * 32));
  };

  f32x4 acc[MR][4];
  const f32x4 z4 = {0.f, 0.f, 0.f, 0.f};
#pragma unroll
  for (int i = 0; i < MR; ++i)
#pragma unroll
    for (int j = 0; j < 4; ++j) acc[i][j] = z4;

  const int sw8 = (quad ^ (lm & 3) ^ ((lm >> 2) & 3)) * 8;  // frag read unit

  const int nt = K >> 5;            // requires nt >= 4 (all shapes ok)
  stage(0); stage(1); stage(2);

  for (int t = 0; t < nt; ++t) {
    if (t + 3 < nt) {
      stage(t + 3);                 // issue BEFORE the wait: stays in flight
      WAITVM(3 * LPT);              // tile t landed; t+1..t+3 still flying
    } else {
      const int rem = nt - 1 - t;
      if (rem == 2)      WAITVM(2 * LPT);
      else if (rem == 1) WAITVM(1 * LPT);
      else               WAITVM(0);
    }
    __builtin_amdgcn_s_barrier();   // all waves' tile-t data visible in LDS

    const int b = t & 3;
    short8 af[MR], bf[4];
#pragma unroll
    for (int i = 0; i < MR; ++i)
      af[i] = *(const short8*)&As[b][(am + i * 16 + lm) * 32 + sw8];
#pragma unroll
    for (int j = 0; j < 4; ++j)
      bf[j] = *(const short8*)&Bs[b][(bn + j * 16 + lm) * 32 + sw8];

    __builtin_amdgcn_s_setprio(1);
#pragma unroll
    for (int i = 0; i < MR; ++i)
#pragma unroll
      for (int j = 0; j < 4; ++j)
        acc[i][j] = __builtin_amdgcn_mfma_f32_16x16x32_bf16(
            af[i], bf[j], acc[i][j], 0, 0, 0);
    __builtin_amdgcn_s_setprio(0);
    __builtin_amdgcn_s_barrier();   // buf b free for the stage at t+1's top
  }

  // C/D layout: col = lane&15, row = quad*4 + r   [m89-verified]
#pragma unroll
  for (int i = 0; i < MR; ++i) {
#pragma unroll
    for (int r = 0; r < 4; ++r) {
      const int grow = m0 + am + i * 16 + quad * 4 + r;
#pragma unroll
      for (int j = 0; j < 4; ++j) {
        const int gcol = n0 + bn + j * 16 + lm;
        if (gcol < N) {
          const size_t idx = (size_t)grow * N + gcol;
          float vacc = acc[i][j][r];
          if (EPI == 0) {
            ((ushort*)Cv)[idx] = f2bf(vacc);
          } else if (EPI == 2) {
            ((float*)Cv)[idx] = vacc + ((const float*)resv)[idx];
          } else if (EPI == 3) {
            float gv = bf2f(((const ushort*)resv)[idx]);
            ((ushort*)Cv)[idx] = f2bf(gv / (1.f + __expf(-gv)) * vacc);
          } else {  // EPI 4: split q / ckv
            if (gcol < 3072)
              ((ushort*)Cv)[(size_t)grow * 3072 + gcol] = f2bf(vacc);
            else
              ((float*)resv)[(size_t)grow * 576 + (gcol - 3072)] = vacc;
          }
        }
      }
    }
  }
}

// ---------------- YaRN RoPE ----------------
__global__ __launch_bounds__(64)
void rope_kernel(ushort* __restrict__ q, const float* __restrict__ ckv,
                 const int* __restrict__ pos_ids, ushort* __restrict__ kpe) {
  const int t = blockIdx.x;
  const int j = threadIdx.x;
  const int j2 = j & 31;
  const float ar = (float)j2 * (1.f / 32.f);
  const float fe = exp2f(-ar * 13.287712379549449f);
  const float fi = fe * 0.025f;
  float ramp = ((float)j2 - 10.f) * (1.f / 13.f);
  ramp = fminf(fmaxf(ramp, 0.f), 1.f);
  const float invf = fi * ramp + fe * (1.f - ramp);
  const float ang = (float)pos_ids[t] * invf;
  float s, c;
  __sincosf(ang, &s, &c);
  const bool lo = j < 32;
  {
    const float* kp = ckv + (size_t)t * 576 + 512;
    float x0 = kp[2 * j2], x1 = kp[2 * j2 + 1];
    float o = lo ? (x0 * c - x1 * s) : (x1 * c + x0 * s);
    kpe[(size_t)t * 64 + j] = f2bf(o);
  }
  for (int h = 0; h < 16; ++h) {
    ushort* qp = q + (size_t)t * 3072 + h * 192 + 128;
    float x0 = bf2f(qp[2 * j2]), x1 = bf2f(qp[2 * j2 + 1]);
    float o = lo ? (x0 * c - x1 * s) : (x1 * c + x0 * s);
    __syncthreads();
    qp[j] = f2bf(o);
  }
}

// ---------------- Flash MFMA attention ----------------
__global__ __launch_bounds__(256, 2)
void attn_mfma(const ushort* __restrict__ q, const ushort* __restrict__ kv,
               const ushort* __restrict__ kpe, ushort* __restrict__ out) {
  const int qt = (int)gridDim.x - 1 - (int)blockIdx.x;
  const int bh = blockIdx.y;
  const int b = bh >> 4, h = bh & 15;
  const int tid = threadIdx.x;
  const int wave = tid >> 6, lane = tid & 63;
  const int lm = lane & 15, quad = lane >> 4;
  const int wq = wave * 32;
  const float scale = 0.07216878364870323f;

  __shared__ __align__(16) char smem[62464];
  ushort (*Ks)[200] = (ushort(*)[200])smem;
  ushort (*Vt)[72]  = (ushort(*)[72])(smem + 25600);
  ushort (*Pm)[72]  = (ushort(*)[72])(smem + 44032);
  ushort (*Qs)[200] = (ushort(*)[200])smem;

  const size_t tok0 = (size_t)b * 2048;
  const int q0 = qt * 128;

  {
    const ushort* qbase = q + (tok0 + q0) * 3072 + (size_t)h * 192;
#pragma unroll
    for (int it = 0; it < 12; ++it) {
      int idx = (it * 256 + tid) * 8;
      int row = idx / 192, col = idx % 192;
      *(uint4*)&Qs[row][col] = *(const uint4*)(qbase + (size_t)row * 3072 + col);
    }
  }
  __syncthreads();
  short8 qf[2][6];
#pragma unroll
  for (int mt = 0; mt < 2; ++mt)
#pragma unroll
    for (int kk = 0; kk < 6; ++kk)
      qf[mt][kk] = *(const short8*)&Qs[wq + mt * 16 + lm][kk * 32 + quad * 8];
  __syncthreads();

  f32x4 o[2][8];
  const f32x4 z4 = {0.f, 0.f, 0.f, 0.f};
#pragma unroll
  for (int mt = 0; mt < 2; ++mt)
#pragma unroll
    for (int nt = 0; nt < 8; ++nt) o[mt][nt] = z4;
  float m_run[8], l_run[8];
#pragma unroll
  for (int i = 0; i < 8; ++i) { m_run[i] = -3.0e38f; l_run[i] = 0.f; }

  const int nkt = 2 * qt + 2;
  for (int kt = 0; kt < nkt; ++kt) {
    const int kb = kt * 64;
    {
      const int krow = tid >> 2, kq = tid & 3;
      const ushort* src = kv + ((tok0 + kb + krow) * 16 + h) * 256 + kq * 32;
#pragma unroll
      for (int i = 0; i < 4; ++i)
        *(uint4*)&Ks[krow][kq * 32 + i * 8] = *(const uint4*)(src + i * 8);
      const ushort* psrc = kpe + (tok0 + kb + krow) * 64 + kq * 16;
      *(uint4*)&Ks[krow][128 + kq * 16]     = *(const uint4*)(psrc);
      *(uint4*)&Ks[krow][128 + kq * 16 + 8] = *(const uint4*)(psrc + 8);
      const int kgrp = (tid & 15) * 4, dgrp = (tid >> 4) * 8;
      uint4 vv[4];
#pragma unroll
      for (int i = 0; i < 4; ++i)
        vv[i] = *(const uint4*)(kv + ((tok0 + kb + kgrp + i) * 16 + h) * 256 + 128 + dgrp);
#pragma unroll
      for (int j = 0; j < 8; ++j) {
        short4v w;
#pragma unroll
        for (int i = 0; i < 4; ++i) w[i] = (short)((const ushort*)&vv[i])[j];
        *(short4v*)&Vt[dgrp + j][kgrp] = w;
      }
    }
    __syncthreads();

    f32x4 s_acc[2][4];
#pragma unroll
    for (int mt = 0; mt < 2; ++mt)
#pragma unroll
      for (int nt = 0; nt < 4; ++nt) s_acc[mt][nt] = z4;
#pragma unroll
    for (int kk = 0; kk < 6; ++kk) {
      short8 kf[4];
#pragma unroll
      for (int nt = 0; nt < 4; ++nt)
        kf[nt] = *(const short8*)&Ks[nt * 16 + lm][kk * 32 + quad * 8];
#pragma unroll
      for (int mt = 0; mt < 2; ++mt)
#pragma unroll
        for (int nt = 0; nt < 4; ++nt)
          s_acc[mt][nt] = __builtin_amdgcn_mfma_f32_16x16x32_bf16(
              qf[mt][kk], kf[nt], s_acc[mt][nt], 0, 0, 0);
    }

    // wave-uniform: interior tiles (all keys <= min q-row of this wave) skip mask
    const bool full = (kb + 63) <= (q0 + wq);
#pragma unroll
    for (int mt = 0; mt < 2; ++mt) {
#pragma unroll
      for (int r = 0; r < 4; ++r) {
        const int qg = q0 + wq + mt * 16 + quad * 4 + r;
        float sv[4];
        float rm = -3.0e38f;
        if (full) {
#pragma unroll
          for (int nt = 0; nt < 4; ++nt) {
            float s = s_acc[mt][nt][r] * scale;
            sv[nt] = s;
            rm = fmaxf(rm, s);
          }
        } else {
#pragma unroll
          for (int nt = 0; nt < 4; ++nt) {
            const int key = kb + nt * 16 + lm;
            float s = s_acc[mt][nt][r] * scale;
            s = (key <= qg) ? s : -3.0e38f;
            sv[nt] = s;
            rm = fmaxf(rm, s);
          }
        }
#pragma unroll
        for (int off = 1; off < 16; off <<= 1) rm = fmaxf(rm, __shfl_xor(rm, off));
        const int li = mt * 4 + r;
        const float mnew = fmaxf(m_run[li], rm);
        const float alpha = __expf(m_run[li] - mnew);
        m_run[li] = mnew;
        float rs = 0.f;
        ushort pb[4];
#pragma unroll
        for (int nt = 0; nt < 4; ++nt) {
          float p = __expf(sv[nt] - mnew);
          rs += p;
          pb[nt] = f2bf(p);
        }
#pragma unroll
        for (int off = 1; off < 16; off <<= 1) rs += __shfl_xor(rs, off);
        l_run[li] = l_run[li] * alpha + rs;
#pragma unroll
        for (int nt = 0; nt < 8; ++nt) o[mt][nt][r] *= alpha;
        const int qrow = wq + mt * 16 + quad * 4 + r;
#pragma unroll
        for (int nt = 0; nt < 4; ++nt) Pm[qrow][nt * 16 + lm] = pb[nt];
      }
    }

#pragma unroll
    for (int kt2 = 0; kt2 < 2; ++kt2) {
      short8 pa[2];
#pragma unroll
      for (int mt = 0; mt < 2; ++mt)
        pa[mt] = *(const short8*)&Pm[wq + mt * 16 + lm][kt2 * 32 + quad * 8];
#pragma unroll
      for (int nt = 0; nt < 8; ++nt) {
        short8 vb = *(const short8*)&Vt[nt * 16 + lm][kt2 * 32 + quad * 8];
#pragma unroll
        for (int mt = 0; mt < 2; ++mt)
          o[mt][nt] = __builtin_amdgcn_mfma_f32_16x16x32_bf16(
              pa[mt], vb, o[mt][nt], 0, 0, 0);
      }
    }
    __syncthreads();
  }

  ushort* obase = out + (tok0 + q0) * 2048 + h * 128;
#pragma unroll
  for (int mt = 0; mt < 2; ++mt) {
#pragma unroll
    for (int r = 0; r < 4; ++r) {
      const int qrow = wq + mt * 16 + quad * 4 + r;
      const float inv = 1.f / l_run[mt * 4 + r];
#pragma unroll
      for (int nt = 0; nt < 8; ++nt)
        obase[(size_t)qrow * 2048 + nt * 16 + lm] = f2bf(o[mt][nt][r] * inv);
    }
  }
}

extern "C" void kernel_launch(void* const* d_in, const int* in_sizes, int n_in,
                              void* d_out, int out_size, void* d_ws, size_t ws_size,
                              hipStream_t stream) {
  const float* hidden = (const float*)d_in[0];
  const int*   pos    = (const int*)d_in[1];
  const float* Wq     = (const float*)d_in[2];
  const float* Wkva   = (const float*)d_in[3];
  const float* w_kvln = (const float*)d_in[4];
  const float* Wkvb   = (const float*)d_in[5];
  const float* Wo     = (const float*)d_in[6];
  const float* Wg     = (const float*)d_in[7];
  const float* Wu     = (const float*)d_in[8];
  const float* Wd     = (const float*)d_in[9];
  const float* w_ln1  = (const float*)d_in[10];
  const float* w_ln2  = (const float*)d_in[11];
  float* out = (float*)d_out;

  char* ws = (char*)d_ws;
  ushort* xn    = (ushort*)(ws);
  char*   R1    = ws + 16777216;
  ushort* qb    = (ushort*)(R1);
  float*  ckv   = (float*)(R1 + 25165824);
  ushort* cn    = (ushort*)(R1 + 34603008);
  ushort* kvb   = (ushort*)(R1 + 38797312);
  ushort* kpe   = (ushort*)(R1 + 72351744);
  ushort* attno = (ushort*)(R1 + 72876032);
  ushort* gb    = (ushort*)(R1);                    // (T,10944) aliases R1
  float*  h1    = (float*)(ws + 196083712);

  char* WSL = ws + 106430464;                       // 89,653,248 B slot region
  ushort* wq_bf   = (ushort*)(WSL);                 // 3072 rows; wkva contiguous after
  ushort* wkva_bf = (ushort*)(WSL + 12582912);      // 576 rows -> combined N=3648
  ushort* wkvb_bf = (ushort*)(WSL + 14942208);
  ushort* wo_bf   = (ushort*)(WSL + 19136512);
  ushort* wg_bf   = (ushort*)(WSL);                 // phase B
  ushort* wu_bf   = (ushort*)(WSL + 44826624);
  ushort* wd_bf   = (ushort*)(WSL + 44826624);      // reuses wu slot after up GEMM

  cvt_bf16<<<3072, 256, 0, stream>>>(Wq,   wq_bf,   786432);
  cvt_bf16<<<576,  256, 0, stream>>>(Wkva, wkva_bf, 147456);
  cvt_bf16<<<1024, 256, 0, stream>>>(Wkvb, wkvb_bf, 262144);
  cvt_bf16<<<2048, 256, 0, stream>>>(Wo,   wo_bf,   524288);
  cvt_bf16<<<10944, 256, 0, stream>>>(Wu,  wu_bf,   2801664);

  rms_bf16<<<4096, 256, 0, stream>>>(hidden, 2048, 2048, 1.f / 2048.f, w_ln1, xn, 2048);
  // merged q + ckv projection (N = 3072 + 576 = 3648, weights contiguous)
  gemm256<4, 2><<<dim3(16, 15), 512, 0, stream>>>(xn, wq_bf, qb, ckv, 4096, 3648, 2048);
  rms_bf16<<<4096, 256, 0, stream>>>(ckv, 576, 512, 1.f / 512.f, w_kvln, cn, 512);
  gemm256<0, 2><<<dim3(16, 16), 512, 0, stream>>>(cn, wkvb_bf, kvb, nullptr, 4096, 4096, 512);
  rope_kernel<<<4096, 64, 0, stream>>>(qb, ckv, pos, kpe);
  attn_mfma<<<dim3(16, 32), 256, 0, stream>>>(qb, kvb, kpe, attno);
  gemm256<2, 1><<<dim3(32, 8), 512, 0, stream>>>(attno, wo_bf, h1, hidden, 4096, 2048, 2048);
  rms_bf16<<<4096, 256, 0, stream>>>(h1, 2048, 2048, 1.f / 2048.f, w_ln2, xn, 2048);

  cvt_bf16<<<10944, 256, 0, stream>>>(Wg, wg_bf, 2801664);
  gemm256<0, 2><<<dim3(16, 43), 512, 0, stream>>>(xn, wg_bf, gb, nullptr, 4096, 10944, 2048);
  gemm256<3, 2><<<dim3(16, 43), 512, 0, stream>>>(xn, wu_bf, gb, gb, 4096, 10944, 2048);
  cvt_bf16<<<10944, 256, 0, stream>>>(Wd, wd_bf, 2801664);
  gemm256<2, 1><<<dim3(32, 8), 512, 0, stream>>>(gb, wd_bf, out, h1, 4096, 2048, 10944);
}

// Round 3
// 1537.976 us; speedup vs baseline: 1.0842x; 1.0842x over previous
//
#include <hip/hip_runtime.h>
#include <hip/hip_bf16.h>
#include <math.h>

// DeepseekV2-Lite decoder layer, MI355X gfx950.
// Round 7: GEMMs rebuilt on the verified m201 8-phase schedule: BK=64,
// 2-K-tile double buffer, half-tile staging (1 per phase, issue stream 1.5
// tiles ahead), ONE counted vmcnt(BMH+2) per K-tile (never 0 mid-loop),
// per-phase double barriers + setprio around each 16-MFMA cluster,
// 128-B LDS rows with the proven XOR-8 granule swizzle (0-conflict pattern).
// BM=256 (BMH=2) for large-N GEMMs, BM=128 (BMH=1) for N=2048 GEMMs.
//
// Shapes: B=2 S=2048 T=4096, H=16, D_NOPE=128 D_ROPE=64 D_Q=192 D_V=128,
// KV_RANK=512, HID=2048, INTER=10944.

typedef short short8 __attribute__((ext_vector_type(8)));
typedef short short4v __attribute__((ext_vector_type(4)));
typedef float f32x4 __attribute__((ext_vector_type(4)));

static __device__ __forceinline__ float bf2f(ushort u) {
  union { uint i; float f; } v; v.i = ((uint)u) << 16; return v.f;
}
static __device__ __forceinline__ ushort f2bf(float x) {
  union { float f; uint i; } v; v.f = x;
  uint r = v.i + 0x7fffu + ((v.i >> 16) & 1u);
  return (ushort)(r >> 16);
}

// async global->LDS, 16B per lane; LDS dest is wave-uniform base + lane*16
static __device__ __forceinline__ void glds16(const ushort* g, ushort* l) {
  __builtin_amdgcn_global_load_lds(
      (const __attribute__((address_space(1))) unsigned int*)g,
      (__attribute__((address_space(3))) unsigned int*)l, 16, 0, 0);
}

#define WAITVM(N) asm volatile("s_waitcnt vmcnt(%0)" ::"n"(N) : "memory")

// ---------------- fp32 -> bf16 weight conversion ----------------
__global__ __launch_bounds__(256)
void cvt_bf16(const float* __restrict__ in, ushort* __restrict__ out, int n8) {
  int i = blockIdx.x * 256 + threadIdx.x;
  if (i >= n8) return;
  float4 a = ((const float4*)in)[2 * i];
  float4 b = ((const float4*)in)[2 * i + 1];
  short8 o;
  o[0] = (short)f2bf(a.x); o[1] = (short)f2bf(a.y);
  o[2] = (short)f2bf(a.z); o[3] = (short)f2bf(a.w);
  o[4] = (short)f2bf(b.x); o[5] = (short)f2bf(b.y);
  o[6] = (short)f2bf(b.z); o[7] = (short)f2bf(b.w);
  ((short8*)out)[i] = o;
}

// ---------------- RMSNorm (fp32 in -> bf16 out) ----------------
__global__ __launch_bounds__(256)
void rms_bf16(const float* __restrict__ in, int istride, int width, float inv_w,
              const float* __restrict__ w, ushort* __restrict__ out, int ostride) {
  const int row = blockIdx.x;
  const float* x = in + (size_t)row * istride;
  float ss = 0.f;
  for (int i = threadIdx.x; i < width; i += 256) { float v = x[i]; ss += v * v; }
#pragma unroll
  for (int off = 32; off > 0; off >>= 1) ss += __shfl_xor(ss, off);
  __shared__ float red[4];
  if ((threadIdx.x & 63) == 0) red[threadIdx.x >> 6] = ss;
  __syncthreads();
  float tot = red[0] + red[1] + red[2] + red[3];
  float scale = rsqrtf(tot * inv_w + 1e-6f);
  ushort* o = out + (size_t)row * ostride;
  for (int i = threadIdx.x; i < width; i += 256) o[i] = f2bf(x[i] * scale * w[i]);
}

// ---------------- 8-phase GEMM: C[M,N] = A[M,K](bf16) @ B[N,K]^T(bf16) -----
// BM = BMH*128, BN = 256, BK = 64. 8 waves (2M x 4N), 512 threads.
// LDS: A,B each split into 2 halves per K-tile, 2-K-tile parity ring.
// Rows are 128 B (64 bf16); granule u of row r stored at u ^ (r&7)
// (verified 0-conflict pattern). Staging: global_load_lds with
// inverse-swizzled global source, linear LDS dest.
// Per K-tile: 4 phases (A0B0)(A0B1)(A1B1)(A1B0), each = {ds_read frags,
// stage 1 half-tile, barrier, setprio1, 16*BMH/2 MFMA, setprio0, barrier}.
// Stage stream: ph0 -> A1(T+1), ph1 -> B0(T+1), ph2 -> A0(T+2), ph3 -> B1(T+2);
// ph3 waits vmcnt(BMH+2): tile T+1 fully landed, 2 halves stay in flight.
// EPI 0: C bf16 ; EPI 2: C f32 = acc + res(f32)
// EPI 3: C bf16 = silu(prev bf16 at resv) * acc
// EPI 4: split QKV epilogue (cols <3072 -> bf16 q stride 3072; else f32 ckv
//        stride 576 at resv)
template<int EPI, int BMH>
__global__ __launch_bounds__(512, 1)
void gemm8p(const ushort* __restrict__ A, const ushort* __restrict__ B,
            void* __restrict__ Cv, const void* __restrict__ resv,
            int M, int N, int K) {
  constexpr int BM = BMH * 128;
  constexpr int MF = BMH * 2;             // m-frags per half per wave
  constexpr int HALF_A = (BM / 2) * 64;   // elems per A half-tile
  constexpr int HALF_B = 128 * 64;
  constexpr int WVN = BMH + 2;            // steady-state vmcnt
  __shared__ __align__(16) ushort As[4 * HALF_A];  // 2 parity x 2 half
  __shared__ __align__(16) ushort Bs[4 * HALF_B];
  const int tid = threadIdx.x;
  const int wave = tid >> 6, lane = tid & 63;
  const int lm = lane & 15, quad = lane >> 4;
  const int wmg = wave >> 2, wng = wave & 3;

  // bijective XCD-aware block swizzle (m204)
  const int gx = gridDim.x;
  int wg = blockIdx.y * gx + blockIdx.x;
  {
    const int nwg = gx * (int)gridDim.y;
    const int q = nwg >> 3, r = nwg & 7;
    const int xcd = wg & 7, i = wg >> 3;
    wg = (xcd < r ? xcd * (q + 1) : r * (q + 1) + (xcd - r) * q) + i;
  }
  const int m0 = (wg % gx) * BM, n0 = (wg / gx) * 256;

  // ---- staging addresses (one glds16 covers 8 rows x 64 cols)
  const int srow8 = lane >> 3;                 // row within 8-row slab
  const int gu8 = ((lane & 7) ^ srow8) * 8;    // inverse-swizzled global unit
  const ushort* gAp[2][BMH];
#pragma unroll
  for (int h = 0; h < 2; ++h)
#pragma unroll
    for (int j = 0; j < BMH; ++j)
      gAp[h][j] = A + (size_t)(m0 + h * (BM / 2) + j * 64 + wave * 8 + srow8) * K + gu8;
  const ushort* gBp[2][2];
#pragma unroll
  for (int h = 0; h < 2; ++h)
#pragma unroll
    for (int j = 0; j < 2; ++j) {
      int br = n0 + h * 128 + j * 64 + wave * 8 + srow8;
      if (br > N - 1) br = N - 1;              // clamp OOB (cols guarded at C)
      gBp[h][j] = B + (size_t)br * K + gu8;
    }

  auto stageA = [&](int par, int h, int t) {
#pragma unroll
    for (int j = 0; j < BMH; ++j)
      glds16(gAp[h][j] + (size_t)t * 64,
             &As[(par * 2 + h) * HALF_A + (j * 64 + wave * 8) * 64]);
  };
  auto stageB = [&](int par, int h, int t) {
#pragma unroll
    for (int j = 0; j < 2; ++j)
      glds16(gBp[h][j] + (size_t)t * 64,
             &Bs[(par * 2 + h) * HALF_B + (j * 64 + wave * 8) * 64]);
  };

  // ---- fragment read offsets (swizzled)
  int aoff[MF], boff[2], pos8[2];
#pragma unroll
  for (int mf = 0; mf < MF; ++mf) aoff[mf] = (wmg * (BM / 4) + mf * 16 + lm) * 64;
#pragma unroll
  for (int nf = 0; nf < 2; ++nf) boff[nf] = (wng * 32 + nf * 16 + lm) * 64;
#pragma unroll
  for (int kk = 0; kk < 2; ++kk) pos8[kk] = ((kk * 4 + quad) ^ (lm & 7)) * 8;

  f32x4 acc[2 * MF][4];
  const f32x4 z4 = {0.f, 0.f, 0.f, 0.f};
#pragma unroll
  for (int i = 0; i < 2 * MF; ++i)
#pragma unroll
    for (int j = 0; j < 4; ++j) acc[i][j] = z4;

  const int NT = K >> 6;
  // prologue stream: A0(0), B1(0), A1(0), B0(0), A0(1), B1(1)
  stageA(0, 0, 0); stageB(0, 1, 0); stageA(0, 1, 0); stageB(0, 0, 0);
  stageA(1, 0, 1); stageB(1, 1, 1);
  WAITVM(WVN);                      // tile 0 landed; A0(1),B1(1) in flight
  __builtin_amdgcn_s_barrier();

  for (int T = 0; T < NT; ++T) {
    const int par = T & 1, nxt = par ^ 1;
    const ushort* Ab0 = &As[(par * 2 + 0) * HALF_A];
    const ushort* Ab1 = &As[(par * 2 + 1) * HALF_A];
    const ushort* Bb0 = &Bs[(par * 2 + 0) * HALF_B];
    const ushort* Bb1 = &Bs[(par * 2 + 1) * HALF_B];
    short8 a0[MF][2], a1[MF][2], b0[2][2], b1[2][2];

    // ---- phase 0: (A0,B0)
#pragma unroll
    for (int mf = 0; mf < MF; ++mf)
#pragma unroll
      for (int kk = 0; kk < 2; ++kk)
        a0[mf][kk] = *(const short8*)(Ab0 + aoff[mf] + pos8[kk]);
#pragma unroll
    for (int nf = 0; nf < 2; ++nf)
#pragma unroll
      for (int kk = 0; kk < 2; ++kk)
        b0[nf][kk] = *(const short8*)(Bb0 + boff[nf] + pos8[kk]);
    if (T + 1 < NT) stageA(nxt, 1, T + 1);
    __builtin_amdgcn_s_barrier();
    __builtin_amdgcn_s_setprio(1);
#pragma unroll
    for (int mf = 0; mf < MF; ++mf)
#pragma unroll
      for (int nf = 0; nf < 2; ++nf)
#pragma unroll
        for (int kk = 0; kk < 2; ++kk)
          acc[mf][nf] = __builtin_amdgcn_mfma_f32_16x16x32_bf16(
              a0[mf][kk], b0[nf][kk], acc[mf][nf], 0, 0, 0);
    __builtin_amdgcn_s_setprio(0);
    __builtin_amdgcn_s_barrier();

    // ---- phase 1: (A0,B1)
#pragma unroll
    for (int nf = 0; nf < 2; ++nf)
#pragma unroll
      for (int kk = 0; kk < 2; ++kk)
        b1[nf][kk] = *(const short8*)(Bb1 + boff[nf] + pos8[kk]);
    if (T + 1 < NT) stageB(nxt, 0, T + 1);
    __builtin_amdgcn_s_barrier();
    __builtin_amdgcn_s_setprio(1);
#pragma unroll
    for (int mf = 0; mf < MF; ++mf)
#pragma unroll
      for (int nf = 0; nf < 2; ++nf)
#pragma unroll
        for (int kk = 0; kk < 2; ++kk)
          acc[mf][2 + nf] = __builtin_amdgcn_mfma_f32_16x16x32_bf16(
              a0[mf][kk], b1[nf][kk], acc[mf][2 + nf], 0, 0, 0);
    __builtin_amdgcn_s_setprio(0);
    __builtin_amdgcn_s_barrier();

    // ---- phase 2: (A1,B1)
#pragma unroll
    for (int mf = 0; mf < MF; ++mf)
#pragma unroll
      for (int kk = 0; kk < 2; ++kk)
        a1[mf][kk] = *(const short8*)(Ab1 + aoff[mf] + pos8[kk]);
    if (T + 2 < NT) stageA(par, 0, T + 2);
    __builtin_amdgcn_s_barrier();
    __builtin_amdgcn_s_setprio(1);
#pragma unroll
    for (int mf = 0; mf < MF; ++mf)
#pragma unroll
      for (int nf = 0; nf < 2; ++nf)
#pragma unroll
        for (int kk = 0; kk < 2; ++kk)
          acc[MF + mf][2 + nf] = __builtin_amdgcn_mfma_f32_16x16x32_bf16(
              a1[mf][kk], b1[nf][kk], acc[MF + mf][2 + nf], 0, 0, 0);
    __builtin_amdgcn_s_setprio(0);
    __builtin_amdgcn_s_barrier();

    // ---- phase 3: (A1,B0)
    if (T + 2 < NT) stageB(par, 1, T + 2);
    if (T + 2 == NT) { WAITVM(0); }          // tail: nothing issued after NT-1
    else if (T + 2 < NT) { WAITVM(WVN); }    // tile T+1 landed, 2 halves flying
    __builtin_amdgcn_s_barrier();
    __builtin_amdgcn_s_setprio(1);
#pragma unroll
    for (int mf = 0; mf < MF; ++mf)
#pragma unroll
      for (int nf = 0; nf < 2; ++nf)
#pragma unroll
        for (int kk = 0; kk < 2; ++kk)
          acc[MF + mf][nf] = __builtin_amdgcn_mfma_f32_16x16x32_bf16(
              a1[mf][kk], b0[nf][kk], acc[MF + mf][nf], 0, 0, 0);
    __builtin_amdgcn_s_setprio(0);
    __builtin_amdgcn_s_barrier();
  }

  // C/D layout: col = lane&15, row = quad*4 + r   [m89-verified]
#pragma unroll
  for (int mh = 0; mh < 2; ++mh)
#pragma unroll
    for (int mf = 0; mf < MF; ++mf)
#pragma unroll
      for (int r = 0; r < 4; ++r) {
        const int grow = m0 + mh * (BM / 2) + wmg * (BM / 4) + mf * 16 + quad * 4 + r;
#pragma unroll
        for (int nh = 0; nh < 2; ++nh)
#pragma unroll
          for (int nf = 0; nf < 2; ++nf) {
            const int gcol = n0 + nh * 128 + wng * 32 + nf * 16 + lm;
            if (gcol < N) {
              const size_t idx = (size_t)grow * N + gcol;
              float vacc = acc[mh * MF + mf][nh * 2 + nf][r];
              if (EPI == 0) {
                ((ushort*)Cv)[idx] = f2bf(vacc);
              } else if (EPI == 2) {
                ((float*)Cv)[idx] = vacc + ((const float*)resv)[idx];
              } else if (EPI == 3) {
                float gv = bf2f(((const ushort*)resv)[idx]);
                ((ushort*)Cv)[idx] = f2bf(gv / (1.f + __expf(-gv)) * vacc);
              } else {  // EPI 4: split q / ckv
                if (gcol < 3072)
                  ((ushort*)Cv)[(size_t)grow * 3072 + gcol] = f2bf(vacc);
                else
                  ((float*)resv)[(size_t)grow * 576 + (gcol - 3072)] = vacc;
              }
            }
          }
      }
}

// ---------------- YaRN RoPE ----------------
__global__ __launch_bounds__(64)
void rope_kernel(ushort* __restrict__ q, const float* __restrict__ ckv,
                 const int* __restrict__ pos_ids, ushort* __restrict__ kpe) {
  const int t = blockIdx.x;
  const int j = threadIdx.x;
  const int j2 = j & 31;
  const float ar = (float)j2 * (1.f / 32.f);
  const float fe = exp2f(-ar * 13.287712379549449f);
  const float fi = fe * 0.025f;
  float ramp = ((float)j2 - 10.f) * (1.f / 13.f);
  ramp = fminf(fmaxf(ramp, 0.f), 1.f);
  const float invf = fi * ramp + fe * (1.f - ramp);
  const float ang = (float)pos_ids[t] * invf;
  float s, c;
  __sincosf(ang, &s, &c);
  const bool lo = j < 32;
  {
    const float* kp = ckv + (size_t)t * 576 + 512;
    float x0 = kp[2 * j2], x1 = kp[2 * j2 + 1];
    float o = lo ? (x0 * c - x1 * s) : (x1 * c + x0 * s);
    kpe[(size_t)t * 64 + j] = f2bf(o);
  }
  for (int h = 0; h < 16; ++h) {
    ushort* qp = q + (size_t)t * 3072 + h * 192 + 128;
    float x0 = bf2f(qp[2 * j2]), x1 = bf2f(qp[2 * j2 + 1]);
    float o = lo ? (x0 * c - x1 * s) : (x1 * c + x0 * s);
    __syncthreads();
    qp[j] = f2bf(o);
  }
}

// ---------------- Flash MFMA attention ----------------
__global__ __launch_bounds__(256, 2)
void attn_mfma(const ushort* __restrict__ q, const ushort* __restrict__ kv,
               const ushort* __restrict__ kpe, ushort* __restrict__ out) {
  const int qt = (int)gridDim.x - 1 - (int)blockIdx.x;
  const int bh = blockIdx.y;
  const int b = bh >> 4, h = bh & 15;
  const int tid = threadIdx.x;
  const int wave = tid >> 6, lane = tid & 63;
  const int lm = lane & 15, quad = lane >> 4;
  const int wq = wave * 32;
  const float scale = 0.07216878364870323f;

  __shared__ __align__(16) char smem[62464];
  ushort (*Ks)[200] = (ushort(*)[200])smem;
  ushort (*Vt)[72]  = (ushort(*)[72])(smem + 25600);
  ushort (*Pm)[72]  = (ushort(*)[72])(smem + 44032);
  ushort (*Qs)[200] = (ushort(*)[200])smem;

  const size_t tok0 = (size_t)b * 2048;
  const int q0 = qt * 128;

  {
    const ushort* qbase = q + (tok0 + q0) * 3072 + (size_t)h * 192;
#pragma unroll
    for (int it = 0; it < 12; ++it) {
      int idx = (it * 256 + tid) * 8;
      int row = idx / 192, col = idx % 192;
      *(uint4*)&Qs[row][col] = *(const uint4*)(qbase + (size_t)row * 3072 + col);
    }
  }
  __syncthreads();
  short8 qf[2][6];
#pragma unroll
  for (int mt = 0; mt < 2; ++mt)
#pragma unroll
    for (int kk = 0; kk < 6; ++kk)
      qf[mt][kk] = *(const short8*)&Qs[wq + mt * 16 + lm][kk * 32 + quad * 8];
  __syncthreads();

  f32x4 o[2][8];
  const f32x4 z4 = {0.f, 0.f, 0.f, 0.f};
#pragma unroll
  for (int mt = 0; mt < 2; ++mt)
#pragma unroll
    for (int nt = 0; nt < 8; ++nt) o[mt][nt] = z4;
  float m_run[8], l_run[8];
#pragma unroll
  for (int i = 0; i < 8; ++i) { m_run[i] = -3.0e38f; l_run[i] = 0.f; }

  const int nkt = 2 * qt + 2;
  for (int kt = 0; kt < nkt; ++kt) {
    const int kb = kt * 64;
    {
      const int krow = tid >> 2, kq = tid & 3;
      const ushort* src = kv + ((tok0 + kb + krow) * 16 + h) * 256 + kq * 32;
#pragma unroll
      for (int i = 0; i < 4; ++i)
        *(uint4*)&Ks[krow][kq * 32 + i * 8] = *(const uint4*)(src + i * 8);
      const ushort* psrc = kpe + (tok0 + kb + krow) * 64 + kq * 16;
      *(uint4*)&Ks[krow][128 + kq * 16]     = *(const uint4*)(psrc);
      *(uint4*)&Ks[krow][128 + kq * 16 + 8] = *(const uint4*)(psrc + 8);
      const int kgrp = (tid & 15) * 4, dgrp = (tid >> 4) * 8;
      uint4 vv[4];
#pragma unroll
      for (int i = 0; i < 4; ++i)
        vv[i] = *(const uint4*)(kv + ((tok0 + kb + kgrp + i) * 16 + h) * 256 + 128 + dgrp);
#pragma unroll
      for (int j = 0; j < 8; ++j) {
        short4v w;
#pragma unroll
        for (int i = 0; i < 4; ++i) w[i] = (short)((const ushort*)&vv[i])[j];
        *(short4v*)&Vt[dgrp + j][kgrp] = w;
      }
    }
    __syncthreads();

    f32x4 s_acc[2][4];
#pragma unroll
    for (int mt = 0; mt < 2; ++mt)
#pragma unroll
      for (int nt = 0; nt < 4; ++nt) s_acc[mt][nt] = z4;
#pragma unroll
    for (int kk = 0; kk < 6; ++kk) {
      short8 kf[4];
#pragma unroll
      for (int nt = 0; nt < 4; ++nt)
        kf[nt] = *(const short8*)&Ks[nt * 16 + lm][kk * 32 + quad * 8];
#pragma unroll
      for (int mt = 0; mt < 2; ++mt)
#pragma unroll
        for (int nt = 0; nt < 4; ++nt)
          s_acc[mt][nt] = __builtin_amdgcn_mfma_f32_16x16x32_bf16(
              qf[mt][kk], kf[nt], s_acc[mt][nt], 0, 0, 0);
    }

    // wave-uniform: interior tiles (all keys <= min q-row of this wave) skip mask
    const bool full = (kb + 63) <= (q0 + wq);
#pragma unroll
    for (int mt = 0; mt < 2; ++mt) {
#pragma unroll
      for (int r = 0; r < 4; ++r) {
        const int qg = q0 + wq + mt * 16 + quad * 4 + r;
        float sv[4];
        float rm = -3.0e38f;
        if (full) {
#pragma unroll
          for (int nt = 0; nt < 4; ++nt) {
            float s = s_acc[mt][nt][r] * scale;
            sv[nt] = s;
            rm = fmaxf(rm, s);
          }
        } else {
#pragma unroll
          for (int nt = 0; nt < 4; ++nt) {
            const int key = kb + nt * 16 + lm;
            float s = s_acc[mt][nt][r] * scale;
            s = (key <= qg) ? s : -3.0e38f;
            sv[nt] = s;
            rm = fmaxf(rm, s);
          }
        }
#pragma unroll
        for (int off = 1; off < 16; off <<= 1) rm = fmaxf(rm, __shfl_xor(rm, off));
        const int li = mt * 4 + r;
        const float mnew = fmaxf(m_run[li], rm);
        const float alpha = __expf(m_run[li] - mnew);
        m_run[li] = mnew;
        float rs = 0.f;
        ushort pb[4];
#pragma unroll
        for (int nt = 0; nt < 4; ++nt) {
          float p = __expf(sv[nt] - mnew);
          rs += p;
          pb[nt] = f2bf(p);
        }
#pragma unroll
        for (int off = 1; off < 16; off <<= 1) rs += __shfl_xor(rs, off);
        l_run[li] = l_run[li] * alpha + rs;
#pragma unroll
        for (int nt = 0; nt < 8; ++nt) o[mt][nt][r] *= alpha;
        const int qrow = wq + mt * 16 + quad * 4 + r;
#pragma unroll
        for (int nt = 0; nt < 4; ++nt) Pm[qrow][nt * 16 + lm] = pb[nt];
      }
    }

#pragma unroll
    for (int kt2 = 0; kt2 < 2; ++kt2) {
      short8 pa[2];
#pragma unroll
      for (int mt = 0; mt < 2; ++mt)
        pa[mt] = *(const short8*)&Pm[wq + mt * 16 + lm][kt2 * 32 + quad * 8];
#pragma unroll
      for (int nt = 0; nt < 8; ++nt) {
        short8 vb = *(const short8*)&Vt[nt * 16 + lm][kt2 * 32 + quad * 8];
#pragma unroll
        for (int mt = 0; mt < 2; ++mt)
          o[mt][nt] = __builtin_amdgcn_mfma_f32_16x16x32_bf16(
              pa[mt], vb, o[mt][nt], 0, 0, 0);
      }
    }
    __syncthreads();
  }

  ushort* obase = out + (tok0 + q0) * 2048 + h * 128;
#pragma unroll
  for (int mt = 0; mt < 2; ++mt) {
#pragma unroll
    for (int r = 0; r < 4; ++r) {
      const int qrow = wq + mt * 16 + quad * 4 + r;
      const float inv = 1.f / l_run[mt * 4 + r];
#pragma unroll
      for (int nt = 0; nt < 8; ++nt)
        obase[(size_t)qrow * 2048 + nt * 16 + lm] = f2bf(o[mt][nt][r] * inv);
    }
  }
}

extern "C" void kernel_launch(void* const* d_in, const int* in_sizes, int n_in,
                              void* d_out, int out_size, void* d_ws, size_t ws_size,
                              hipStream_t stream) {
  const float* hidden = (const float*)d_in[0];
  const int*   pos    = (const int*)d_in[1];
  const float* Wq     = (const float*)d_in[2];
  const float* Wkva   = (const float*)d_in[3];
  const float* w_kvln = (const float*)d_in[4];
  const float* Wkvb   = (const float*)d_in[5];
  const float* Wo     = (const float*)d_in[6];
  const float* Wg     = (const float*)d_in[7];
  const float* Wu     = (const float*)d_in[8];
  const float* Wd     = (const float*)d_in[9];
  const float* w_ln1  = (const float*)d_in[10];
  const float* w_ln2  = (const float*)d_in[11];
  float* out = (float*)d_out;

  char* ws = (char*)d_ws;
  ushort* xn    = (ushort*)(ws);
  char*   R1    = ws + 16777216;
  ushort* qb    = (ushort*)(R1);
  float*  ckv   = (float*)(R1 + 25165824);
  ushort* cn    = (ushort*)(R1 + 34603008);
  ushort* kvb   = (ushort*)(R1 + 38797312);
  ushort* kpe   = (ushort*)(R1 + 72351744);
  ushort* attno = (ushort*)(R1 + 72876032);
  ushort* gb    = (ushort*)(R1);                    // (T,10944) aliases R1
  float*  h1    = (float*)(ws + 196083712);

  char* WSL = ws + 106430464;                       // 89,653,248 B slot region
  ushort* wq_bf   = (ushort*)(WSL);                 // 3072 rows; wkva contiguous after
  ushort* wkva_bf = (ushort*)(WSL + 12582912);      // 576 rows -> combined N=3648
  ushort* wkvb_bf = (ushort*)(WSL + 14942208);
  ushort* wo_bf   = (ushort*)(WSL + 19136512);
  ushort* wg_bf   = (ushort*)(WSL);                 // phase B
  ushort* wu_bf   = (ushort*)(WSL + 44826624);
  ushort* wd_bf   = (ushort*)(WSL + 44826624);      // reuses wu slot after up GEMM

  cvt_bf16<<<3072, 256, 0, stream>>>(Wq,   wq_bf,   786432);
  cvt_bf16<<<576,  256, 0, stream>>>(Wkva, wkva_bf, 147456);
  cvt_bf16<<<1024, 256, 0, stream>>>(Wkvb, wkvb_bf, 262144);
  cvt_bf16<<<2048, 256, 0, stream>>>(Wo,   wo_bf,   524288);
  cvt_bf16<<<10944, 256, 0, stream>>>(Wu,  wu_bf,   2801664);

  rms_bf16<<<4096, 256, 0, stream>>>(hidden, 2048, 2048, 1.f / 2048.f, w_ln1, xn, 2048);
  // merged q + ckv projection (N = 3072 + 576 = 3648, weights contiguous)
  gemm8p<4, 2><<<dim3(16, 15), 512, 0, stream>>>(xn, wq_bf, qb, ckv, 4096, 3648, 2048);
  rms_bf16<<<4096, 256, 0, stream>>>(ckv, 576, 512, 1.f / 512.f, w_kvln, cn, 512);
  gemm8p<0, 2><<<dim3(16, 16), 512, 0, stream>>>(cn, wkvb_bf, kvb, nullptr, 4096, 4096, 512);
  rope_kernel<<<4096, 64, 0, stream>>>(qb, ckv, pos, kpe);
  attn_mfma<<<dim3(16, 32), 256, 0, stream>>>(qb, kvb, kpe, attno);
  gemm8p<2, 1><<<dim3(32, 8), 512, 0, stream>>>(attno, wo_bf, h1, hidden, 4096, 2048, 2048);
  rms_bf16<<<4096, 256, 0, stream>>>(h1, 2048, 2048, 1.f / 2048.f, w_ln2, xn, 2048);

  cvt_bf16<<<10944, 256, 0, stream>>>(Wg, wg_bf, 2801664);
  gemm8p<0, 2><<<dim3(16, 43), 512, 0, stream>>>(xn, wg_bf, gb, nullptr, 4096, 10944, 2048);
  gemm8p<3, 2><<<dim3(16, 43), 512, 0, stream>>>(xn, wu_bf, gb, gb, 4096, 10944, 2048);
  cvt_bf16<<<10944, 256, 0, stream>>>(Wd, wd_bf, 2801664);
  gemm8p<2, 1><<<dim3(32, 8), 512, 0, stream>>>(gb, wd_bf, out, h1, 4096, 2048, 10944);
}